// Round 4
// baseline (699.100 us; speedup 1.0000x reference)
//
#include <hip/hip_runtime.h>

// Partial-CRF NLL, single-wave scan blocks. 64 blocks x 64 threads (1 wave).
// Wave owns 16 chains = 8 batches x {all-paths, gold}. Per step:
//   new^T[tag][chain] = sum_k E^T[tag][k] * P^T[k][chain]   (28x mfma 16x16x32 bf16)
//   then w = D * cscale * mult,  mult = exp(emit) (gold rows: * um)
// E^T lives in 112 VGPRs (A-frags; mapping verified in R3, absmax 0.0).
// P bf16 in LDS [16][136]; in-place update, masked chains skip their writes
// (mask-carry). Deferred rescale: cscale = rcp(R[1]) via one __shfl; logZ
// accumulates log(s1) on active steps. NO barriers anywhere (single wave;
// LDS ordering via lgkmcnt). mult staged to LDS bf16 2 steps ahead
// (double reg-set software pipeline, ~1100 cyc load cover).

typedef short bf16x8 __attribute__((ext_vector_type(8)));
typedef short s16x4  __attribute__((ext_vector_type(4)));
typedef float f32x4  __attribute__((ext_vector_type(4)));

constexpr int T  = 512, L = 102;
constexpr int NT = 7;      // tag tiles: 112 padded tags
constexpr int PS = 136;    // P row stride (s16): 128 K-pad + slack, 272B rows
constexpr int MS = 132;    // mult row stride (s16)

__device__ __forceinline__ float bf2f(short s) {
  return __uint_as_float(((unsigned int)(unsigned short)s) << 16);
}
__device__ __forceinline__ short f2bf(float x) {  // RNE (cold paths only)
  unsigned int u = __float_as_uint(x);
  u += 0x7fffu + ((u >> 16) & 1u);
  return (short)(u >> 16);
}

__global__ __launch_bounds__(64, 1)
void crf_scan(const float* __restrict__ emit,
              const float* __restrict__ trans,
              const unsigned char* __restrict__ mask_b,
              const unsigned char* __restrict__ um_b,
              float* __restrict__ partials)
{
  const int lane  = threadIdx.x;
  const int c     = lane & 15;       // chain 0..15
  const int hi    = lane >> 4;       // 0..3
  const int b8    = blockIdx.x * 8;
  const int myb   = c >> 1;
  const int batch = b8 + myb;
  const int goldc = c & 1;
  // bool layout: um[0,0,1] always True -> byte1==1 iff uint8, else LE int32
  const int ush = (um_b[1] != 0) ? 0 : 2;

  __shared__ __align__(16) short Pl[16][PS];
  __shared__ __align__(16) short Ml[2][16][MS];
  __shared__ unsigned char Kmask[8][520];

  // ---- E^T A-frags in registers: ef[Tt][kk], lane holds (tag=16Tt+c, k=32kk+8hi+j)
  bf16x8 ef[NT][4];
#pragma unroll
  for (int Tt = 0; Tt < NT; ++Tt) {
    const int tag = 16 * Tt + c;
#pragma unroll
    for (int kk = 0; kk < 4; ++kk) {
      bf16x8 v;
#pragma unroll
      for (int j = 0; j < 8; ++j) {
        const int k = 32 * kk + 8 * hi + j;
        float e = 0.f;
        if (tag < L && k < L) e = __expf(trans[k * L + tag]);
        v[j] = f2bf(e);
      }
      ef[Tt][kk] = v;
    }
  }

  // ---- one-time LDS staging: mask bytes + zero P (incl. K-pad) ----
  for (int i = lane; i < 8 * T; i += 64) {
    const int bb = i >> 9, tt = i & 511;
    Kmask[bb][tt] = mask_b[(((size_t)(b8 + bb)) * T + tt) << ush];
  }
  for (int i = lane; i < 16 * PS; i += 64) (&Pl[0][0])[i] = 0;

  // ---- t = 0 init: R0 = exp(e0 + trans[START][tag]) (gold: um-gated) ----
  float v1cap = 0.f;
  {
    const size_t e0b = (size_t)batch * T * L;
#pragma unroll
    for (int Tt = 0; Tt < NT; ++Tt) {
      s16x4 o;
#pragma unroll
      for (int r = 0; r < 4; ++r) {
        const int tag = 16 * Tt + 4 * hi + r;
        float v = 0.f;
        if (tag < L) {
          v = __expf(emit[e0b + tag] + trans[100 * L + tag]);
          if (goldc && !um_b[(e0b + tag) << ush]) v = 0.f;
        }
        if (Tt == 0 && r == 1) v1cap = v;
        o[r] = f2bf(v);
      }
      *(s16x4*)&Pl[c][16 * Tt + 4 * hi] = o;
    }
  }
  float s1v    = __shfl(v1cap, c);   // R[1] of my chain (>0 always)
  float cscale = __builtin_amdgcn_rcpf(s1v);
  float logZ   = 0.f;

  // ---- staging pipeline: mult[t] = exp(emit[t]) (gold rows x um) as bf16 ---
  const int  tagp   = 2 * lane;                       // 0..126
  const int  tagc   = (tagp <= 100) ? tagp : 100;     // safe addresses
  const bool tvalid = (tagp <= 100);

  float2 eA[8], eB[8];
  unsigned char a0[8], a1[8], b0[8], b1[8];

  auto issueS = [&](int t, float2* ee, unsigned char* u0, unsigned char* u1) {
    const int tc = (t < T) ? t : T - 1;
#pragma unroll
    for (int i = 0; i < 8; ++i) {
      const size_t base = ((size_t)(b8 + i) * T + tc) * L;
      ee[i] = *(const float2*)(emit + base + tagc);
      u0[i] = um_b[(base + tagc) << ush];
      u1[i] = um_b[(base + tagc + 1) << ush];
    }
  };
  auto writeS = [&](int t, const float2* ee, const unsigned char* u0,
                    const unsigned char* u1) {
    const int p = t & 1;
#pragma unroll
    for (int i = 0; i < 8; ++i) {
      const float e0 = tvalid ? __expf(ee[i].x) : 0.f;
      const float e1 = tvalid ? __expf(ee[i].y) : 0.f;
      const float g0 = u0[i] ? e0 : 0.f;
      const float g1 = u1[i] ? e1 : 0.f;
      unsigned int pe, pg;
      asm("v_cvt_pk_bf16_f32 %0, %1, %2" : "=v"(pe) : "v"(e0), "v"(e1));
      asm("v_cvt_pk_bf16_f32 %0, %1, %2" : "=v"(pg) : "v"(g0), "v"(g1));
      *(unsigned int*)&Ml[p][2 * i][tagp]     = pe;  // even chain: all-paths
      *(unsigned int*)&Ml[p][2 * i + 1][tagp] = pg;  // odd chain: gold
    }
  };

  auto body = [&](int t, bool toA) {
    // 1. mask (per-chain; t==512 dummy step forces copy)
    const int mmv = (t < T) ? (int)Kmask[myb][t] : 0;
    // 2. issue global loads for t+2 into set A/B
    if (toA) issueS(t + 2, eA, a0, a1); else issueS(t + 2, eB, b0, b1);
    // 3. B-frags from current P
    const bf16x8 q0 = *(const bf16x8*)&Pl[c][0  + 8 * hi];
    const bf16x8 q1 = *(const bf16x8*)&Pl[c][32 + 8 * hi];
    const bf16x8 q2 = *(const bf16x8*)&Pl[c][64 + 8 * hi];
    const bf16x8 q3 = *(const bf16x8*)&Pl[c][96 + 8 * hi];
    // 4. MFMAs: D[Tt] = E^T(tile) x P^T
    f32x4 d[NT];
#pragma unroll
    for (int Tt = 0; Tt < NT; ++Tt)
      d[Tt] = __builtin_amdgcn_mfma_f32_16x16x32_bf16(ef[Tt][0], q0,
                                                      (f32x4){0.f,0.f,0.f,0.f}, 0, 0, 0);
#pragma unroll
    for (int Tt = 0; Tt < NT; ++Tt)
      d[Tt] = __builtin_amdgcn_mfma_f32_16x16x32_bf16(ef[Tt][1], q1, d[Tt], 0, 0, 0);
#pragma unroll
    for (int Tt = 0; Tt < NT; ++Tt)
      d[Tt] = __builtin_amdgcn_mfma_f32_16x16x32_bf16(ef[Tt][2], q2, d[Tt], 0, 0, 0);
#pragma unroll
    for (int Tt = 0; Tt < NT; ++Tt)
      d[Tt] = __builtin_amdgcn_mfma_f32_16x16x32_bf16(ef[Tt][3], q3, d[Tt], 0, 0, 0);
    // 5. epilogue: w = D * cscale * mult; conditional in-place P update
    const int p = t & 1;
    float v1loc = 0.f;
#pragma unroll
    for (int Tt = 0; Tt < NT; ++Tt) {
      const s16x4 m4 = *(const s16x4*)&Ml[p][c][16 * Tt + 4 * hi];
      const float w0 = d[Tt][0] * cscale * bf2f(m4[0]);
      const float w1 = d[Tt][1] * cscale * bf2f(m4[1]);
      const float w2 = d[Tt][2] * cscale * bf2f(m4[2]);
      const float w3 = d[Tt][3] * cscale * bf2f(m4[3]);
      if (Tt == 0) v1loc = w1;
      unsigned int lo, hiw;
      asm("v_cvt_pk_bf16_f32 %0, %1, %2" : "=v"(lo)  : "v"(w0), "v"(w1));
      asm("v_cvt_pk_bf16_f32 %0, %1, %2" : "=v"(hiw) : "v"(w2), "v"(w3));
      if (mmv) *(uint2*)&Pl[c][16 * Tt + 4 * hi] = make_uint2(lo, hiw);
    }
    // 6. deferred-rescale bookkeeping
    const float s1n = __shfl(v1loc, c);
    logZ += mmv ? __logf(s1v) : 0.f;
    s1v   = mmv ? s1n : s1v;
    cscale = __builtin_amdgcn_rcpf(s1v);
    // 7. finish staging for t+1 from the OTHER set (loads issued at body t-1)
    if (toA) writeS(t + 1, eB, b0, b1); else writeS(t + 1, eA, a0, a1);
  };

  // prologue: mult(1) synchronous; issue set B for t=2
  issueS(1, eA, a0, a1);
  writeS(1, eA, a0, a1);
  issueS(2, eB, b0, b1);

  for (int t = 1; t < 512; t += 2) {
    body(t, true);        // odd body: issues A(t+2), writes B -> mult(t+1)
    body(t + 1, false);   // even body (t=512 is a harmless masked dummy)
  }

  // ---- final: score = logZ + log sum_n R[n] * exp(trans[n][STOP]) ----
  float tot = 0.f;
#pragma unroll
  for (int Tt = 0; Tt < NT; ++Tt) {
    const s16x4 pv = *(const s16x4*)&Pl[c][16 * Tt + 4 * hi];
#pragma unroll
    for (int r = 0; r < 4; ++r) {
      const int tag = 16 * Tt + 4 * hi + r;
      if (tag < L) tot += bf2f(pv[r]) * __expf(trans[tag * L + 101]);
    }
  }
  tot += __shfl_xor(tot, 16);
  tot += __shfl_xor(tot, 32);
  const float score = logZ + __logf(tot);
  float sgn = goldc ? -score : score;
  sgn += __shfl_xor(sgn, 1);
  sgn += __shfl_xor(sgn, 2);
  sgn += __shfl_xor(sgn, 4);
  sgn += __shfl_xor(sgn, 8);
  if (lane == 0) partials[blockIdx.x] = sgn;
}

__global__ void reduce_partials(const float* __restrict__ part,
                                float* __restrict__ out) {
  float v = part[threadIdx.x];
#pragma unroll
  for (int s = 1; s < 64; s <<= 1) v += __shfl_xor(v, s);
  if (threadIdx.x == 0) out[0] = v;
}

extern "C" void kernel_launch(void* const* d_in, const int* in_sizes, int n_in,
                              void* d_out, int out_size, void* d_ws,
                              size_t ws_size, hipStream_t stream) {
  const float* emit = (const float*)d_in[0];
  const float* trn  = (const float*)d_in[1];
  const unsigned char* msk = (const unsigned char*)d_in[2];
  const unsigned char* umk = (const unsigned char*)d_in[3];
  float* out = (float*)d_out;
  float* pw  = (float*)d_ws;   // 64 block partials

  crf_scan<<<dim3(64), dim3(64), 0, stream>>>(emit, trn, msk, umk, pw);
  reduce_partials<<<dim3(1), dim3(64), 0, stream>>>(pw, out);
}

// Round 5
// 460.761 us; speedup vs baseline: 1.5173x; 1.5173x over previous
//
#include <hip/hip_runtime.h>

// Partial-CRF NLL, producer/consumer wave-specialized scan.
// 64 blocks x 128 threads = {wave0: consumer, wave1: producer}.
// Block owns 16 chains = 8 batches x {all-paths, gold}.
//
// Consumer (serial recurrence, per step t):
//   new^T[tag][chain] = sum_k E^T[tag][k] * P^T[k][chain]  (28x mfma 16x16x32 bf16)
//   w = D * cscale * mult[t];  conditional (per-chain mask) in-place P update.
//   Deferred rescale: cscale = rcp(P[1]) via one shfl; logZ += log(s1).
// Producer: mult[t] = exp(emit[t]) (gold rows x um) -> bf16 LDS ring of 8
//   slabs, 4-deep static register prefetch (struct sets, no runtime indexing).
// Sync: monotonic LDS flags, volatile polls, lgkmcnt(0) release fences.
// Math identical to R4 (absmax 0.0 there).

typedef short bf16x8 __attribute__((ext_vector_type(8)));
typedef short s16x4  __attribute__((ext_vector_type(4)));
typedef float f32x4  __attribute__((ext_vector_type(4)));

constexpr int T  = 512, L = 102;
constexpr int NT = 7;      // tag tiles (112 padded tags)
constexpr int PS = 136;    // P row stride (shorts), 272B rows, 16B-aligned
constexpr int MS = 132;    // mult row stride (shorts), 8B-aligned rows
constexpr int NS = 8;      // ring slabs

__device__ __forceinline__ float bf2f(short s) {
  return __uint_as_float(((unsigned int)(unsigned short)s) << 16);
}
__device__ __forceinline__ short f2bf(float x) {  // RNE (cold paths only)
  unsigned int u = __float_as_uint(x);
  u += 0x7fffu + ((u >> 16) & 1u);
  return (short)(u >> 16);
}

__global__ __launch_bounds__(128, 1)
void crf_scan(const float* __restrict__ emit,
              const float* __restrict__ trans,
              const unsigned char* __restrict__ mask_b,
              const unsigned char* __restrict__ um_b,
              float* __restrict__ partials)
{
  const int tid  = threadIdx.x;
  const int wid  = tid >> 6;
  const int lane = tid & 63;
  const int b8   = blockIdx.x * 8;
  // bool layout: um[0,0,1] always True -> byte1==1 iff uint8, else LE int32
  const int ush = (um_b[1] != 0) ? 0 : 2;

  __shared__ __align__(16) short Pl[16][PS];
  __shared__ __align__(16) short Ml[NS][16][MS];
  __shared__ unsigned char Kmask[8][T];
  __shared__ int sflags[2];          // [0] = producer progress, [1] = consumer

  volatile int* pfv = (volatile int*)&sflags[0];
  volatile int* cfv = (volatile int*)&sflags[1];

  if (wid == 1) {
    // ================= producer wave =================
    if (lane == 0) sflags[0] = 0;
    const int  tagp   = 2 * lane;                    // 0..126
    const int  tagc   = (tagp <= 100) ? tagp : 100;  // clamped safe addr
    const bool tvalid = (tagp <= 100);

    for (int i = lane; i < 8 * T; i += 64) {         // mask bytes, one-time
      const int bb = i >> 9, tt = i & 511;
      Kmask[bb][tt] = mask_b[(((size_t)(b8 + bb)) * T + tt) << ush];
    }

    struct SetS { float2 e[8]; unsigned char u0[8]; unsigned char u1[8]; };
    SetS sA, sB, sC, sD;                             // static names (rule #20)

    auto issue = [&](int t, SetS& S) {
      const int tc = (t < T) ? t : T - 1;
#pragma unroll
      for (int i = 0; i < 8; ++i) {
        const size_t base = ((size_t)(b8 + i) * T + tc) * (size_t)L;
        S.e[i]  = *(const float2*)(emit + base + tagc);
        S.u0[i] = um_b[(base + tagc) << ush];
        S.u1[i] = um_b[(base + tagc + 1) << ush];
      }
    };
    auto stagewr = [&](int t, SetS& S) {
      short* slab = &Ml[t & (NS - 1)][0][0];
#pragma unroll
      for (int i = 0; i < 8; ++i) {
        const float e0 = tvalid ? __expf(S.e[i].x) : 0.f;
        const float e1 = tvalid ? __expf(S.e[i].y) : 0.f;
        const float g0 = S.u0[i] ? e0 : 0.f;
        const float g1 = S.u1[i] ? e1 : 0.f;
        unsigned int pe, pg;
        asm("v_cvt_pk_bf16_f32 %0, %1, %2" : "=v"(pe) : "v"(e0), "v"(e1));
        asm("v_cvt_pk_bf16_f32 %0, %1, %2" : "=v"(pg) : "v"(g0), "v"(g1));
        *(unsigned int*)(slab + (2 * i)     * MS + tagp) = pe;  // all-paths
        *(unsigned int*)(slab + (2 * i + 1) * MS + tagp) = pg;  // gold
      }
    };

    __syncthreads();                                 // flags/Kmask/Pl ready
    issue(1, sA); issue(2, sB); issue(3, sC); issue(4, sD);
    int pseen = 0;

#define PRODBODY(tt, S)                                                      \
    {                                                                        \
      if ((tt) > NS && pseen < (tt) - NS) {                                  \
        int v; do { v = *cfv; } while (v < (tt) - NS);                       \
        pseen = v;                                                           \
      }                                                                      \
      stagewr((tt), S);                                                      \
      asm volatile("s_waitcnt lgkmcnt(0)" ::: "memory");                     \
      if (lane == 0) *pfv = (tt);                                            \
      issue((tt) + 4, S);                                                    \
    }

    for (int t0 = 1; t0 <= 509; t0 += 4) {
      PRODBODY(t0,     sA)
      PRODBODY(t0 + 1, sB)
      PRODBODY(t0 + 2, sC)
      PRODBODY(t0 + 3, sD)   // t=512 body is a harmless dummy stage
    }
#undef PRODBODY
  } else {
    // ================= consumer wave =================
    if (lane == 0) sflags[1] = 0;
    const int c     = lane & 15;          // chain 0..15
    const int hi    = lane >> 4;          // 0..3
    const int myb   = c >> 1;
    const int batch = b8 + myb;
    const int goldc = c & 1;

    for (int i = lane; i < 16 * PS; i += 64) (&Pl[0][0])[i] = 0;

    // E^T A-frags: lane holds (tag = 16Tt + c, k = 32kk + 8hi + j)
    bf16x8 ef[NT][4];
#pragma unroll
    for (int Tt = 0; Tt < NT; ++Tt) {
      const int tag = 16 * Tt + c;
#pragma unroll
      for (int kk = 0; kk < 4; ++kk) {
        bf16x8 v;
#pragma unroll
        for (int j = 0; j < 8; ++j) {
          const int k = 32 * kk + 8 * hi + j;
          float e = 0.f;
          if (tag < L && k < L) e = __expf(trans[k * L + tag]);
          v[j] = f2bf(e);
        }
        ef[Tt][kk] = v;
      }
    }

    __syncthreads();                                 // Kmask now valid

    // t = 0 init: P0 = exp(e0 + trans[START][tag]) (gold: um-gated)
    float v1cap = 0.f;
    {
      const size_t e0b = (size_t)batch * T * L;
#pragma unroll
      for (int Tt = 0; Tt < NT; ++Tt) {
        s16x4 o;
#pragma unroll
        for (int r = 0; r < 4; ++r) {
          const int tag = 16 * Tt + 4 * hi + r;
          float v = 0.f;
          if (tag < L) {
            v = __expf(emit[e0b + tag] + trans[100 * L + tag]);
            if (goldc && !um_b[(e0b + tag) << ush]) v = 0.f;
          }
          if (Tt == 0 && r == 1) v1cap = v;
          o[r] = f2bf(v);
        }
        *(s16x4*)&Pl[c][16 * Tt + 4 * hi] = o;
      }
    }
    float s1v    = __shfl(v1cap, c);      // P[1] of my chain (> 0 always)
    float cscale = __builtin_amdgcn_rcpf(s1v);
    float logZ   = 0.f;
    int   seen   = 0;

    for (int t = 1; t < T; ++t) {
      if (seen < t) {                      // amortized slab-availability poll
        int v; do { v = *pfv; } while (v < t);
        seen = v;
      }
      __builtin_amdgcn_sched_barrier(0);   // no slab reads above the poll

      const int mmv = (int)Kmask[myb][t];
      const short* slabp = &Ml[t & (NS - 1)][0][0];
      const short* Prow  = &Pl[c][0];

      const bf16x8 q0 = *(const bf16x8*)(Prow + 0  + 8 * hi);
      const bf16x8 q1 = *(const bf16x8*)(Prow + 32 + 8 * hi);
      const bf16x8 q2 = *(const bf16x8*)(Prow + 64 + 8 * hi);
      const bf16x8 q3 = *(const bf16x8*)(Prow + 96 + 8 * hi);

      f32x4 d[NT];
#pragma unroll
      for (int Tt = 0; Tt < NT; ++Tt)
        d[Tt] = __builtin_amdgcn_mfma_f32_16x16x32_bf16(
            ef[Tt][0], q0, (f32x4){0.f, 0.f, 0.f, 0.f}, 0, 0, 0);
#pragma unroll
      for (int Tt = 0; Tt < NT; ++Tt)
        d[Tt] = __builtin_amdgcn_mfma_f32_16x16x32_bf16(ef[Tt][1], q1, d[Tt], 0, 0, 0);
#pragma unroll
      for (int Tt = 0; Tt < NT; ++Tt)
        d[Tt] = __builtin_amdgcn_mfma_f32_16x16x32_bf16(ef[Tt][2], q2, d[Tt], 0, 0, 0);
#pragma unroll
      for (int Tt = 0; Tt < NT; ++Tt)
        d[Tt] = __builtin_amdgcn_mfma_f32_16x16x32_bf16(ef[Tt][3], q3, d[Tt], 0, 0, 0);

      float v1loc = 0.f;
#pragma unroll
      for (int Tt = 0; Tt < NT; ++Tt) {
        const s16x4 m4 = *(const s16x4*)(slabp + c * MS + 16 * Tt + 4 * hi);
        const float w0 = d[Tt][0] * cscale * bf2f(m4[0]);
        const float w1 = d[Tt][1] * cscale * bf2f(m4[1]);
        const float w2 = d[Tt][2] * cscale * bf2f(m4[2]);
        const float w3 = d[Tt][3] * cscale * bf2f(m4[3]);
        if (Tt == 0) v1loc = w1;
        unsigned int lo, hiw;
        asm("v_cvt_pk_bf16_f32 %0, %1, %2" : "=v"(lo)  : "v"(w0), "v"(w1));
        asm("v_cvt_pk_bf16_f32 %0, %1, %2" : "=v"(hiw) : "v"(w2), "v"(w3));
        if (mmv) *(uint2*)&Pl[c][16 * Tt + 4 * hi] = make_uint2(lo, hiw);
      }

      const float s1n = __shfl(v1loc, c);  // candidate new P[1]
      logZ  += mmv ? __logf(s1v) : 0.f;
      s1v    = mmv ? s1n : s1v;
      cscale = __builtin_amdgcn_rcpf(s1v);

      asm volatile("s_waitcnt lgkmcnt(0)" ::: "memory");  // release slab t
      if (lane == 0) *cfv = t;
    }

    // final: score = logZ + log sum_n P[n] * exp(trans[n][STOP])
    float tot = 0.f;
#pragma unroll
    for (int Tt = 0; Tt < NT; ++Tt) {
      const s16x4 pv = *(const s16x4*)&Pl[c][16 * Tt + 4 * hi];
#pragma unroll
      for (int r = 0; r < 4; ++r) {
        const int tag = 16 * Tt + 4 * hi + r;
        if (tag < L) tot += bf2f(pv[r]) * __expf(trans[tag * L + 101]);
      }
    }
    tot += __shfl_xor(tot, 16);
    tot += __shfl_xor(tot, 32);
    const float score = logZ + __logf(tot);
    float sgn = goldc ? -score : score;
    sgn += __shfl_xor(sgn, 1);
    sgn += __shfl_xor(sgn, 2);
    sgn += __shfl_xor(sgn, 4);
    sgn += __shfl_xor(sgn, 8);
    if (lane == 0) partials[blockIdx.x] = sgn;
  }
}

__global__ void reduce_partials(const float* __restrict__ part,
                                float* __restrict__ out) {
  float v = part[threadIdx.x];
#pragma unroll
  for (int s = 1; s < 64; s <<= 1) v += __shfl_xor(v, s);
  if (threadIdx.x == 0) out[0] = v;
}

extern "C" void kernel_launch(void* const* d_in, const int* in_sizes, int n_in,
                              void* d_out, int out_size, void* d_ws,
                              size_t ws_size, hipStream_t stream) {
  const float* emit = (const float*)d_in[0];
  const float* trn  = (const float*)d_in[1];
  const unsigned char* msk = (const unsigned char*)d_in[2];
  const unsigned char* umk = (const unsigned char*)d_in[3];
  float* out = (float*)d_out;
  float* pw  = (float*)d_ws;   // 64 block partials

  crf_scan<<<dim3(64), dim3(128), 0, stream>>>(emit, trn, msk, umk, pw);
  reduce_partials<<<dim3(1), dim3(64), 0, stream>>>(pw, out);
}

// Round 6
// 314.630 us; speedup vs baseline: 2.2220x; 1.4645x over previous
//
#include <hip/hip_runtime.h>

// Partial-CRF NLL, producer/consumer scan with REGISTER-RESIDENT state.
// 64 blocks x 192 threads = {wave0: consumer, wave1+2: producers}.
// Block owns 16 chains = 8 batches x {all-paths, gold}.
//
// sigma-permuted tile layout: D position (Tt,hi,r) holds tag
//   sigma(Tt,hi,r) = 32*(Tt>>1)+4*(Tt&1)+8*hi+r   (Tt<6)
//                  = 96+4*hi+r                     (Tt==6)
// With this map, next step's B-fragments q0..q2 are the lane's OWN pk
// registers (D==B layout); only tile 6 needs 4 ds_bpermute + 4 ANDs.
// P never touches LDS. mask is monotone (t < length), so rescale only
// active chains, every 4th step (s = new P[1]; frozen: s=1, log s = 0).
// Producers stage mult[t] = exp(emit) (gold rows x um) into a 16-slab ring,
// global-tag columns (sigma positions are 4 consecutive global tags).
// Sync: monotonic LDS flags, volatile polls, fake-dep asm (no sched_barrier),
// consumer releases every 4 steps.

typedef short bf16x8 __attribute__((ext_vector_type(8)));
typedef short s16x4  __attribute__((ext_vector_type(4)));
typedef float f32x4  __attribute__((ext_vector_type(4)));

constexpr int T = 512, L = 102;
constexpr int MS   = 132;        // slab row stride (shorts)
constexpr int NS   = 16;         // ring slabs
constexpr int SLAB = 16 * MS;    // shorts per slab

__device__ __forceinline__ float bf2f(short s) {
  return __uint_as_float(((unsigned)(unsigned short)s) << 16);
}
__device__ __forceinline__ short f2bf(float x) {  // RNE, cold paths
  unsigned u = __float_as_uint(x);
  u += 0x7fffu + ((u >> 16) & 1u);
  return (short)(u >> 16);
}
__device__ __forceinline__ bf16x8 mk8(unsigned a, unsigned b, unsigned c,
                                      unsigned d) {
  union { unsigned u[4]; bf16x8 v; } x;
  x.u[0] = a; x.u[1] = b; x.u[2] = c; x.u[3] = d;
  return x.v;
}

// epilogue for one tile (expands inside STEP scope)
#define ETILE(Tt, MM, MMVv, RESv)                                            \
  {                                                                          \
    float w0 = dd[Tt][0] * bf2f(MM[0]);                                      \
    float w1 = dd[Tt][1] * bf2f(MM[1]);                                      \
    float w2 = dd[Tt][2] * bf2f(MM[2]);                                      \
    float w3 = dd[Tt][3] * bf2f(MM[3]);                                      \
    if (RESv) { w0 *= cs; w1 *= cs; w2 *= cs; w3 *= cs; }                    \
    unsigned lo_, hi_;                                                       \
    asm("v_cvt_pk_bf16_f32 %0, %1, %2" : "=v"(lo_) : "v"(w0), "v"(w1));      \
    asm("v_cvt_pk_bf16_f32 %0, %1, %2" : "=v"(hi_) : "v"(w2), "v"(w3));      \
    pkA[Tt] = (MMVv) ? lo_ : pkA[Tt];                                        \
    pkB[Tt] = (MMVv) ? hi_ : pkB[Tt];                                        \
  }

#define STEP(SB, MMVv, RESv)                                                 \
  {                                                                          \
    const short* sl = mlb + (SB) + c * MS;                                   \
    const s16x4 mm0 = *(const s16x4*)(sl + 0  + 8 * hi);                     \
    const s16x4 mm1 = *(const s16x4*)(sl + 4  + 8 * hi);                     \
    const s16x4 mm2 = *(const s16x4*)(sl + 32 + 8 * hi);                     \
    const s16x4 mm3 = *(const s16x4*)(sl + 36 + 8 * hi);                     \
    const s16x4 mm4 = *(const s16x4*)(sl + 64 + 8 * hi);                     \
    const s16x4 mm5 = *(const s16x4*)(sl + 68 + 8 * hi);                     \
    const s16x4 mm6 = *(const s16x4*)(sl + 96 + 4 * hi);                     \
    const unsigned q3d0 =                                                    \
        ((unsigned)__builtin_amdgcn_ds_bpermute(bpa, (int)pkA[6])) & himask; \
    const unsigned q3d1 =                                                    \
        ((unsigned)__builtin_amdgcn_ds_bpermute(bpa, (int)pkB[6])) & himask; \
    const unsigned q3d2 =                                                    \
        ((unsigned)__builtin_amdgcn_ds_bpermute(bpb, (int)pkA[6])) & himask; \
    const unsigned q3d3 =                                                    \
        ((unsigned)__builtin_amdgcn_ds_bpermute(bpb, (int)pkB[6])) & himask; \
    const bf16x8 q0 = mk8(pkA[0], pkB[0], pkA[1], pkB[1]);                   \
    const bf16x8 q1 = mk8(pkA[2], pkB[2], pkA[3], pkB[3]);                   \
    const bf16x8 q2 = mk8(pkA[4], pkB[4], pkA[5], pkB[5]);                   \
    const bf16x8 q3 = mk8(q3d0, q3d1, q3d2, q3d3);                           \
    f32x4 dd[7];                                                             \
    _Pragma("unroll") for (int Tt = 0; Tt < 7; ++Tt)                         \
        dd[Tt] = __builtin_amdgcn_mfma_f32_16x16x32_bf16(                    \
            ef[Tt][0], q0, (f32x4){0.f, 0.f, 0.f, 0.f}, 0, 0, 0);            \
    _Pragma("unroll") for (int Tt = 0; Tt < 7; ++Tt)                         \
        dd[Tt] = __builtin_amdgcn_mfma_f32_16x16x32_bf16(ef[Tt][1], q1,      \
                                                         dd[Tt], 0, 0, 0);   \
    _Pragma("unroll") for (int Tt = 0; Tt < 7; ++Tt)                         \
        dd[Tt] = __builtin_amdgcn_mfma_f32_16x16x32_bf16(ef[Tt][2], q2,      \
                                                         dd[Tt], 0, 0, 0);   \
    _Pragma("unroll") for (int Tt = 0; Tt < 7; ++Tt)                         \
        dd[Tt] = __builtin_amdgcn_mfma_f32_16x16x32_bf16(ef[Tt][3], q3,      \
                                                         dd[Tt], 0, 0, 0);   \
    float cs = 1.f;                                                          \
    if (RESv) {                                                              \
      const float w1r  = dd[0][1] * bf2f(mm0[1]);                            \
      const float spre = (MMVv) ? w1r : 1.0f;                                \
      const float sh   = __shfl(spre, c);                                    \
      cs = __builtin_amdgcn_rcpf(sh);                                        \
      logZ += __logf(sh);                                                    \
    }                                                                        \
    ETILE(0, mm0, MMVv, RESv)                                                \
    ETILE(1, mm1, MMVv, RESv)                                                \
    ETILE(2, mm2, MMVv, RESv)                                                \
    ETILE(3, mm3, MMVv, RESv)                                                \
    ETILE(4, mm4, MMVv, RESv)                                                \
    ETILE(5, mm5, MMVv, RESv)                                                \
    ETILE(6, mm6, MMVv, RESv)                                                \
  }

__global__ __launch_bounds__(192, 1)
void crf_scan(const float* __restrict__ emit,
              const float* __restrict__ trans,
              const unsigned char* __restrict__ mask_b,
              const unsigned char* __restrict__ um_b,
              float* __restrict__ partials)
{
  const int tid = threadIdx.x, wid = tid >> 6, lane = tid & 63;
  const int b8 = blockIdx.x * 8;
  // bool layout: um[0,0,1] always True -> byte1==1 iff uint8, else LE int32
  const int ush = (um_b[1] != 0) ? 0 : 2;

  __shared__ __align__(16) short Ml[NS][16][MS];
  __shared__ unsigned char Kmask[8][T];
  __shared__ int sflags[3];   // [0],[1]: producer progress; [2]: consumer

  volatile int* pf0 = (volatile int*)&sflags[0];
  volatile int* pf1 = (volatile int*)&sflags[1];
  volatile int* cfv = (volatile int*)&sflags[2];

  if (wid != 0) {
    // ===================== producer waves (wid 1,2) =====================
    const int pw   = wid - 1;
    const int boff = pw * 4;                       // my 4 batches
    const int tagp = 2 * lane;
    const int tagc = (tagp <= 100) ? tagp : 100;
    const bool tv  = (tagp <= 100);

    for (int i = lane; i < 4 * T; i += 64) {       // my Kmask rows
      const int bb = i >> 9, tt = i & 511;
      Kmask[boff + bb][tt] =
          mask_b[(((size_t)(b8 + boff + bb)) * T + tt) << ush];
    }

    struct SetS { float2 e[4]; int u0[4]; int u1[4]; };
    SetS sA, sB, sC, sD;                           // static names

    auto issue = [&](int t, SetS& S) {
      const int tc = (t < T) ? t : T - 1;
#pragma unroll
      for (int i = 0; i < 4; ++i) {
        const size_t base = ((size_t)(b8 + boff + i) * T + tc) * (size_t)L;
        S.e[i] = *(const float2*)(emit + base + tagc);
        if (ush == 0) {
          const unsigned short us = *(const unsigned short*)(um_b + base + tagc);
          S.u0[i] = us & 255; S.u1[i] = us >> 8;
        } else {
          const uint2 uv = *(const uint2*)(um_b + ((base + tagc) << 2));
          S.u0[i] = (int)uv.x; S.u1[i] = (int)uv.y;
        }
      }
    };
    auto stagewr = [&](int t, SetS& S) {
      short* slab = &Ml[t & (NS - 1)][0][0];
#pragma unroll
      for (int i = 0; i < 4; ++i) {
        const float e0 = tv ? __expf(S.e[i].x) : 0.f;
        const float e1 = tv ? __expf(S.e[i].y) : 0.f;
        const float g0 = S.u0[i] ? e0 : 0.f;
        const float g1 = S.u1[i] ? e1 : 0.f;
        unsigned pe, pg;
        asm("v_cvt_pk_bf16_f32 %0, %1, %2" : "=v"(pe) : "v"(e0), "v"(e1));
        asm("v_cvt_pk_bf16_f32 %0, %1, %2" : "=v"(pg) : "v"(g0), "v"(g1));
        *(unsigned*)(slab + (2 * (boff + i))     * MS + tagp) = pe;  // all
        *(unsigned*)(slab + (2 * (boff + i) + 1) * MS + tagp) = pg;  // gold
      }
    };

    __syncthreads();
    issue(1, sA); issue(2, sB); issue(3, sC); issue(4, sD);
    int csn = 0;
    volatile int* myf = (pw == 0) ? pf0 : pf1;

#define PB(tt, S)                                              \
    {                                                          \
      if ((tt) > NS && csn < (tt) - NS) {                      \
        int v; do { v = *cfv; } while (v < (tt) - NS);         \
        csn = v;                                               \
      }                                                        \
      stagewr((tt), S);                                        \
      asm volatile("s_waitcnt lgkmcnt(0)" ::: "memory");       \
      if (lane == 0) *myf = (tt);                              \
      issue((tt) + 4, S);                                      \
    }
    for (int t0 = 1; t0 <= 505; t0 += 4) {
      PB(t0, sA) PB(t0 + 1, sB) PB(t0 + 2, sC) PB(t0 + 3, sD)
    }
    PB(509, sA) PB(510, sB) PB(511, sC)
#undef PB
  } else {
    // ========================= consumer wave =========================
    if (lane == 0) { sflags[0] = 0; sflags[1] = 0; sflags[2] = 0; }
    const int c = lane & 15, hi = lane >> 4;
    const int myb = c >> 1, batch = b8 + myb, goldc = c & 1;

    // A-frags, sigma row map: row rho=c of tile Tt -> tag g(Tt,c)
    bf16x8 ef[7][4];
#pragma unroll
    for (int Tt = 0; Tt < 7; ++Tt) {
      const int g = (Tt < 6)
          ? (32 * (Tt >> 1) + 4 * (Tt & 1) + 8 * (c >> 2) + (c & 3))
          : (96 + c);
#pragma unroll
      for (int kk = 0; kk < 4; ++kk) {
        bf16x8 v;
#pragma unroll
        for (int j = 0; j < 8; ++j) {
          const int k = 32 * kk + 8 * hi + j;
          float e = 0.f;
          if (k < L && g < L) e = __expf(trans[k * L + g]);
          v[j] = f2bf(e);
        }
        ef[Tt][kk] = v;
      }
    }

    // t = 0 init -> pk registers (sigma layout)
    unsigned pkA[7], pkB[7];
    const size_t e0b = (size_t)batch * T * L;
#pragma unroll
    for (int Tt = 0; Tt < 7; ++Tt) {
      const int s0 = (Tt < 6) ? (32 * (Tt >> 1) + 4 * (Tt & 1) + 8 * hi)
                              : (96 + 4 * hi);
      float w[4];
      if (Tt < 6) {
        const float4 ev = *(const float4*)(emit + e0b + s0);
        const float evv[4] = {ev.x, ev.y, ev.z, ev.w};
#pragma unroll
        for (int r = 0; r < 4; ++r) {
          const int tg = s0 + r;
          float x = __expf(evv[r] + trans[100 * L + tg]);
          if (goldc && !um_b[((size_t)(e0b + tg)) << ush]) x = 0.f;
          w[r] = x;
        }
      } else {
#pragma unroll
        for (int r = 0; r < 4; ++r) {
          const int tg = s0 + r;
          float x = 0.f;
          if (tg < L) {
            x = __expf(emit[e0b + tg] + trans[100 * L + tg]);
            if (goldc && !um_b[((size_t)(e0b + tg)) << ush]) x = 0.f;
          }
          w[r] = x;
        }
      }
      asm("v_cvt_pk_bf16_f32 %0, %1, %2" : "=v"(pkA[Tt]) : "v"(w[0]), "v"(w[1]));
      asm("v_cvt_pk_bf16_f32 %0, %1, %2" : "=v"(pkB[Tt]) : "v"(w[2]), "v"(w[3]));
    }

    const int bpa = (c + 16 * ((2 * hi) & 3)) << 2;       // tile-6 bpermute
    const int bpb = (c + 16 * ((2 * hi + 1) & 3)) << 2;
    const unsigned himask = (hi < 2) ? 0xffffffffu : 0u;  // zero K rows >=112
    const short* mlb = &Ml[0][0][0];
    const unsigned* kmr = (const unsigned*)&Kmask[myb][0];

    float logZ = 0.f;
    int seen = 0;

    __syncthreads();

    for (int t0 = 1; t0 <= 505; t0 += 4) {
      const int t3 = t0 + 3;
      if (seen < t3) {
        int v0, v1;
        do { v0 = *pf0; v1 = *pf1; } while (v0 < t3 || v1 < t3);
        seen = (v0 < v1) ? v0 : v1;
      }
      int sb0 = (t0 & 15) * SLAB;
      int sb1 = ((t0 + 1) & 15) * SLAB;
      int sb2 = ((t0 + 2) & 15) * SLAB;
      int sb3 = ((t0 + 3) & 15) * SLAB;
      asm volatile("" : "+v"(sb0), "+v"(sb1), "+v"(sb2), "+v"(sb3) : "v"(seen));
      const unsigned kl = kmr[(t0 - 1) >> 2];          // bytes t0-1..t0+2
      const unsigned kh = kmr[((t0 - 1) >> 2) + 1];    // byte  t0+3
      const unsigned m0 = (kl >> 8) & 255u, m1 = (kl >> 16) & 255u;
      const unsigned m2 = kl >> 24,         m3 = kh & 255u;
      STEP(sb0, m0, false)
      STEP(sb1, m1, false)
      STEP(sb2, m2, false)
      STEP(sb3, m3, true)
      asm volatile("s_waitcnt lgkmcnt(0)" ::: "memory");
      if (lane == 0) *cfv = t3;
    }
    {   // tail t = 509..511
      if (seen < 511) {
        int v0, v1;
        do { v0 = *pf0; v1 = *pf1; } while (v0 < 511 || v1 < 511);
        seen = (v0 < v1) ? v0 : v1;
      }
      int sb0 = (509 & 15) * SLAB, sb1 = (510 & 15) * SLAB,
          sb2 = (511 & 15) * SLAB;
      asm volatile("" : "+v"(sb0), "+v"(sb1), "+v"(sb2) : "v"(seen));
      const unsigned kl = kmr[127];                    // bytes 508..511
      const unsigned m0 = (kl >> 8) & 255u, m1 = (kl >> 16) & 255u;
      const unsigned m2 = kl >> 24;
      STEP(sb0, m0, false)
      STEP(sb1, m1, false)
      STEP(sb2, m2, false)
    }

    // final: score = logZ + log sum_tag P[tag] * exp(trans[tag][STOP])
    float tot = 0.f;
#pragma unroll
    for (int Tt = 0; Tt < 7; ++Tt) {
      const int s0 = (Tt < 6) ? (32 * (Tt >> 1) + 4 * (Tt & 1) + 8 * hi)
                              : (96 + 4 * hi);
#pragma unroll
      for (int r = 0; r < 4; ++r) {
        const int tg = s0 + r;
        if (tg < L) {
          const unsigned pv = (r < 2) ? pkA[Tt] : pkB[Tt];
          const short bb = (short)((r & 1) ? (pv >> 16) : (pv & 0xffffu));
          tot += bf2f(bb) * __expf(trans[tg * L + 101]);
        }
      }
    }
    tot += __shfl_xor(tot, 16);
    tot += __shfl_xor(tot, 32);
    const float score = logZ + __logf(tot);
    float sgn = goldc ? -score : score;
    sgn += __shfl_xor(sgn, 1);
    sgn += __shfl_xor(sgn, 2);
    sgn += __shfl_xor(sgn, 4);
    sgn += __shfl_xor(sgn, 8);
    if (lane == 0) partials[blockIdx.x] = sgn;
  }
}

__global__ void reduce_partials(const float* __restrict__ part,
                                float* __restrict__ out) {
  float v = part[threadIdx.x];
#pragma unroll
  for (int s = 1; s < 64; s <<= 1) v += __shfl_xor(v, s);
  if (threadIdx.x == 0) out[0] = v;
}

extern "C" void kernel_launch(void* const* d_in, const int* in_sizes, int n_in,
                              void* d_out, int out_size, void* d_ws,
                              size_t ws_size, hipStream_t stream) {
  const float* emit = (const float*)d_in[0];
  const float* trn  = (const float*)d_in[1];
  const unsigned char* msk = (const unsigned char*)d_in[2];
  const unsigned char* umk = (const unsigned char*)d_in[3];
  float* out = (float*)d_out;
  float* pw  = (float*)d_ws;   // 64 block partials

  crf_scan<<<dim3(64), dim3(192), 0, stream>>>(emit, trn, msk, umk, pw);
  reduce_partials<<<dim3(1), dim3(64), 0, stream>>>(pw, out);
}